// Round 2
// baseline (142.354 us; speedup 1.0000x reference)
//
#include <hip/hip_runtime.h>

// KnowledgeGraphEmbedding: out[4][P]
//   dist[p] = || Lp_w[p] @ wi - Rp_w[p] @ wj ||^2
//   out = { dist*is_edge, dist*is_not, is_edge, is_not }
//
// Memory-bound: 2 * P*H*E*4B = 737 MB streamed once. Roofline ~117 us @ 6.3 TB/s.
// R1: hoist loop-invariant wi/wj fragments to registers (no LDS in hot loop),
//     process 2 rows per iteration for deeper outstanding-load queue.

#define KGE_P 1024
#define KGE_H 300
#define KGE_E 300
#define KGE_E4 75   // float4 chunks per row
#define KGE_TAILC 11 // KGE_E4 - 64 chunks handled by lanes 0..10

__device__ __forceinline__ float dot4(float4 x, float4 y) {
    return x.x * y.x + x.y * y.y + x.z * y.z + x.w * y.w;
}

__global__ __launch_bounds__(256) void kge_kernel(
    const float* __restrict__ tag_rep,
    const float* __restrict__ Lp_w,
    const float* __restrict__ Rp_w,
    const int*   __restrict__ relation,
    const int*   __restrict__ tag1_idx,
    const int*   __restrict__ tag2_idx,
    float*       __restrict__ out)
{
    __shared__ float s_wi[KGE_E];
    __shared__ float s_wj[KGE_E];
    __shared__ float s_wave[4];

    const int p    = blockIdx.x;
    const int tid  = threadIdx.x;
    const int lane = tid & 63;
    const int wave = tid >> 6;

    // Stage the two tag-embedding rows into LDS (once), then hoist each lane's
    // fixed fragments into registers.
    {
        const int t1 = tag1_idx[0];
        const int t2 = tag2_idx[0];
        const float* wi = tag_rep + (size_t)t1 * KGE_E;
        const float* wj = tag_rep + (size_t)t2 * KGE_E;
        for (int i = tid; i < KGE_E; i += 256) {
            s_wi[i] = wi[i];
            s_wj[i] = wj[i];
        }
    }
    __syncthreads();

    const float4* s_wi4 = (const float4*)s_wi;
    const float4* s_wj4 = (const float4*)s_wj;

    const float4 a0 = s_wi4[lane];
    const float4 b0 = s_wj4[lane];
    float4 a1 = make_float4(0.f, 0.f, 0.f, 0.f);
    float4 b1 = a1;
    if (lane < KGE_TAILC) {
        a1 = s_wi4[64 + lane];
        b1 = s_wj4[64 + lane];
    }

    const float4* __restrict__ Lbase = (const float4*)(Lp_w + (size_t)p * KGE_H * KGE_E);
    const float4* __restrict__ Rbase = (const float4*)(Rp_w + (size_t)p * KGE_H * KGE_E);

    float dist_acc = 0.0f;

    // Each wave owns 75 rows: h = wave, wave+4, ..., wave+296.
    // Main loop: 2 rows per iteration (37 pairs), then 1 tail row.
    int h = wave;
    for (; h + 4 < KGE_H; h += 8) {
        const float4* __restrict__ L0 = Lbase + (size_t)h * KGE_E4;
        const float4* __restrict__ R0 = Rbase + (size_t)h * KGE_E4;
        const float4* __restrict__ L1 = L0 + 4 * KGE_E4;
        const float4* __restrict__ R1 = R0 + 4 * KGE_E4;

        float4 l0 = L0[lane];
        float4 r0 = R0[lane];
        float4 l1 = L1[lane];
        float4 r1 = R1[lane];

        float p0 = dot4(l0, a0) - dot4(r0, b0);
        float p1 = dot4(l1, a0) - dot4(r1, b0);

        if (lane < KGE_TAILC) {
            float4 l0b = L0[64 + lane];
            float4 r0b = R0[64 + lane];
            float4 l1b = L1[64 + lane];
            float4 r1b = R1[64 + lane];
            p0 += dot4(l0b, a1) - dot4(r0b, b1);
            p1 += dot4(l1b, a1) - dot4(r1b, b1);
        }

        #pragma unroll
        for (int off = 32; off >= 1; off >>= 1) {
            p0 += __shfl_xor(p0, off, 64);
            p1 += __shfl_xor(p1, off, 64);
        }
        dist_acc += p0 * p0 + p1 * p1;
    }
    // Tail row (75 rows per wave is odd).
    for (; h < KGE_H; h += 4) {
        const float4* __restrict__ L0 = Lbase + (size_t)h * KGE_E4;
        const float4* __restrict__ R0 = Rbase + (size_t)h * KGE_E4;
        float4 l0 = L0[lane];
        float4 r0 = R0[lane];
        float p0 = dot4(l0, a0) - dot4(r0, b0);
        if (lane < KGE_TAILC) {
            float4 l0b = L0[64 + lane];
            float4 r0b = R0[64 + lane];
            p0 += dot4(l0b, a1) - dot4(r0b, b1);
        }
        #pragma unroll
        for (int off = 32; off >= 1; off >>= 1)
            p0 += __shfl_xor(p0, off, 64);
        dist_acc += p0 * p0;
    }

    if (lane == 0) s_wave[wave] = dist_acc;
    __syncthreads();

    if (tid == 0) {
        const float dist = s_wave[0] + s_wave[1] + s_wave[2] + s_wave[3];
        const int rel = relation[p];
        const float is_edge = (rel == 1) ? 1.0f : 0.0f;
        const float is_not  = (rel == 0) ? 1.0f : 0.0f;
        out[0 * KGE_P + p] = dist * is_edge;
        out[1 * KGE_P + p] = dist * is_not;
        out[2 * KGE_P + p] = is_edge;
        out[3 * KGE_P + p] = is_not;
    }
}

extern "C" void kernel_launch(void* const* d_in, const int* in_sizes, int n_in,
                              void* d_out, int out_size, void* d_ws, size_t ws_size,
                              hipStream_t stream) {
    const float* tag_rep  = (const float*)d_in[0];
    const float* Lp_w     = (const float*)d_in[1];
    const float* Rp_w     = (const float*)d_in[2];
    const int*   relation = (const int*)d_in[3];
    const int*   tag1_idx = (const int*)d_in[4];
    const int*   tag2_idx = (const int*)d_in[5];
    float*       out      = (float*)d_out;

    kge_kernel<<<KGE_P, 256, 0, stream>>>(tag_rep, Lp_w, Rp_w,
                                          relation, tag1_idx, tag2_idx, out);
}